// Round 6
// baseline (889.176 us; speedup 1.0000x reference)
//
#include <hip/hip_runtime.h>
#include <hip/hip_bf16.h>
#include <cstdint>

#define NN    50000
#define NE    1600000
#define NG    512
#define F     64        // ATOM_FEA
#define ED    32        // EDGE_DIM
#define ZIN   160       // 2F + ED
#define NC    128       // fused Wf|Ws output cols
#define HF    128       // H_FEA
#define NCONV 3
#define BN_EPS 1e-5f
#define EB    128       // edges per block
#define MS    66        // mT row stride in bf16 (33 u32) -> conflict-light

typedef __bf16 bf16_t;
typedef bf16_t bf16x8 __attribute__((ext_vector_type(8)));
typedef float  f32x4  __attribute__((ext_vector_type(4)));

__device__ __forceinline__ float blo(uint32_t u) { union { uint32_t x; float f; } t; t.x = u << 16;          return t.f; }
__device__ __forceinline__ float bhi(uint32_t u) { union { uint32_t x; float f; } t; t.x = u & 0xffff0000u;  return t.f; }

__global__ void k_embed(const int* __restrict__ x, const float* __restrict__ emb,
                        float* __restrict__ h32, bf16_t* __restrict__ hb) {
  int i = blockIdx.x * 256 + threadIdx.x;
  if (i >= NN * F) return;
  int node = i >> 6, c = i & 63;
  float v = emb[x[node] * F + c];
  h32[i] = v;
  hb[i] = (bf16_t)v;
}

// Wt layout: pre-fragmented for 16x16x32 MFMA B-operand, per layer:
//   Wt[((l*5 + ks)*8 + n)*512 + lane*8 + idx]
//   lane: q4=lane>>4, lc=lane&15; col c = n*16+lc; k = 32*ks + q4*4 + (idx&3) + (idx>>2)*16
__global__ void k_wprep(const float* __restrict__ Wf, const float* __restrict__ Ws,
                        bf16_t* __restrict__ Wt) {
  int i = blockIdx.x * 256 + threadIdx.x;  // NCONV*ZIN*NC = 61440
  if (i >= NCONV * ZIN * NC) return;
  int l = i / 20480, r = i % 20480;
  int tile = r / 512, r3 = r % 512;
  int ks = tile / 8, n = tile % 8;
  int lane = r3 >> 3, idx = r3 & 7;
  int q4 = lane >> 4, lc = lane & 15;
  int c = n * 16 + lc;
  int k = 32 * ks + q4 * 4 + (idx & 3) + (idx >> 2) * 16;
  float v = (c < F) ? Wf[(l * ZIN + k) * F + c] : Ws[(l * ZIN + k) * F + (c - F)];
  Wt[i] = (bf16_t)v;
}

// ---- counting sort by dst ----
__global__ void k_hist(const int* __restrict__ ei, int* __restrict__ cnt) {
  int e = blockIdx.x * 256 + threadIdx.x;
  if (e < NE) atomicAdd(&cnt[ei[NE + e]], 1);
}

__global__ void k_scan(const int* __restrict__ cnt, int* __restrict__ off) {
  __shared__ int ts[1024];
  const int t = threadIdx.x;
  const int CH = 49;                 // 1024*49 = 50176 >= NN
  const int base = t * CH;
  int s = 0;
  for (int i = 0; i < CH; ++i) { int idx = base + i; if (idx < NN) s += cnt[idx]; }
  ts[t] = s;
  __syncthreads();
  for (int d = 1; d < 1024; d <<= 1) {
    int v = (t >= d) ? ts[t - d] : 0;
    __syncthreads();
    ts[t] += v;
    __syncthreads();
  }
  int run = (t == 0) ? 0 : ts[t - 1];
  for (int i = 0; i < CH; ++i) {
    int idx = base + i;
    if (idx < NN) { off[idx] = run; run += cnt[idx]; }
  }
}

__global__ void k_scatter(const int* __restrict__ ei, const float* __restrict__ ea,
                          int* __restrict__ head, int* __restrict__ srcs,
                          int* __restrict__ dsts, bf16_t* __restrict__ eas) {
  int e = blockIdx.x * 256 + threadIdx.x;
  if (e >= NE) return;
  int d = ei[NE + e], s = ei[e];
  int p = atomicAdd(&head[d], 1);
  dsts[p] = d; srcs[p] = s;
  const float* pa = ea + (size_t)e * ED;
  bf16_t* pe = eas + (size_t)p * ED;
  #pragma unroll
  for (int q = 0; q < ED; q += 8) {
    float4 x0 = *(const float4*)(pa + q), x1 = *(const float4*)(pa + q + 4);
    union { bf16_t h[8]; uint4 u; } pk;
    pk.h[0] = (bf16_t)x0.x; pk.h[1] = (bf16_t)x0.y; pk.h[2] = (bf16_t)x0.z; pk.h[3] = (bf16_t)x0.w;
    pk.h[4] = (bf16_t)x1.x; pk.h[5] = (bf16_t)x1.y; pk.h[6] = (bf16_t)x1.z; pk.h[7] = (bf16_t)x1.w;
    *(uint4*)(pe + q) = pk.u;
  }
}

// 512 threads, 8 waves, 128 edges/block: each wave = one 16-edge row-tile x 128 cols.
// 16x16x32 MFMA: acc 8x f32x4 = 32 regs, A-frags 10x uint2 = 20 regs -> target <=84 VGPR
// LDS: Bsh 40960 (mT [128][66] bf16 = 16896 overlaps after K-loop) + dstT 512 = 41472 B -> 3 blocks/CU
__launch_bounds__(512, 6)
__global__ void k_edges(const int* __restrict__ srcs, const int* __restrict__ dsts,
                        const bf16_t* __restrict__ eas, const bf16_t* __restrict__ hb,
                        const bf16_t* __restrict__ Wt,
                        const float* __restrict__ bfv, const float* __restrict__ bsv,
                        float* __restrict__ agg, int layer) {
  extern __shared__ char smem[];
  bf16_t* Bsh  = (bf16_t*)smem;                       // [20480] pre-fragmented (dead after K-loop)
  bf16_t* mT   = (bf16_t*)smem;                       // [128][MS] messages (overlaps Bsh)
  int*    dstT = (int*)(smem + 40960);                // [128]

  const int tid = threadIdx.x;
  const int e0  = blockIdx.x * EB;

  const int w  = tid >> 6;
  const int l  = tid & 63;
  const int lc = l & 15;
  const int q4 = l >> 4;
  const int el = w * 16 + lc;       // this lane's edge row (local)

  // long-latency loads first
  const int dv = dsts[e0 + el];
  const int sv = srcs[e0 + el];
  if (tid < EB) dstT[tid] = dsts[e0 + tid];

  // per-lane bias values (folded into acc init via MFMA C-in)
  const float* bfl = bfv + layer * F;
  const float* bsl = bsv + layer * F;
  float bfc[4], bsc[4];
  #pragma unroll
  for (int n = 0; n < 4; ++n) { bfc[n] = bfl[n * 16 + lc]; bsc[n] = bsl[n * 16 + lc]; }

  // gather A-fragments from global. split-half k-map: elems 0-3 k=32ks+q4*4+j, elems 4-7 +16.
  const char* dp = (const char*)(hb + (size_t)dv * F);
  const char* sp = (const char*)(hb + (size_t)sv * F);
  const char* ep = (const char*)(eas + (size_t)(e0 + el) * ED);
  uint2 dq[4], sq[4], eq[2];
  #pragma unroll
  for (int j = 0; j < 4; ++j) dq[j] = *(const uint2*)(dp + q4 * 8 + j * 32);
  #pragma unroll
  for (int j = 0; j < 4; ++j) sq[j] = *(const uint2*)(sp + q4 * 8 + j * 32);
  #pragma unroll
  for (int j = 0; j < 2; ++j) eq[j] = *(const uint2*)(ep + q4 * 8 + j * 32);

  // stage B: 40960 B = 2560 uint4, 5 per thread
  {
    const uint4* Wg = (const uint4*)(Wt + (size_t)layer * NC * ZIN);
    uint4 breg[5];
    #pragma unroll
    for (int t = 0; t < 5; ++t) breg[t] = Wg[tid + t * 512];
    uint4* Bv = (uint4*)Bsh;
    #pragma unroll
    for (int t = 0; t < 5; ++t) Bv[tid + t * 512] = breg[t];
  }
  __syncthreads();

  f32x4 acc[8];
  #pragma unroll
  for (int n = 0; n < 4; ++n) {
    #pragma unroll
    for (int r = 0; r < 4; ++r) { acc[n][r] = bfc[n]; acc[n + 4][r] = bsc[n]; }
  }

  #pragma unroll
  for (int ks = 0; ks < 5; ++ks) {
    union { uint2 u[2]; bf16x8 v; } a;
    a.u[0] = (ks < 2) ? dq[2 * ks]     : (ks < 4) ? sq[2 * (ks - 2)]     : eq[0];
    a.u[1] = (ks < 2) ? dq[2 * ks + 1] : (ks < 4) ? sq[2 * (ks - 2) + 1] : eq[1];
    #pragma unroll
    for (int n = 0; n < 8; ++n) {
      bf16x8 b = *(const bf16x8*)(Bsh + ((ks * 8 + n) * 64 + l) * 8);  // ds_read_b128, stride-1
      acc[n] = __builtin_amdgcn_mfma_f32_16x16x32_bf16(a.v, b, acc[n], 0, 0, 0);
    }
  }

  __syncthreads();   // all waves done with Bsh before mT overwrites it

  // epilogue: m = sigmoid(f)*softplus(s) -> bf16 mT. C/D: col=lane&15, row=(lane>>4)*4+reg (m89)
  bf16_t* mw = mT + w * 16 * MS;
  const float L2E = 1.4426950408889634f, LN2 = 0.6931471805599453f;
  #pragma unroll
  for (int n = 0; n < 4; ++n) {
    const int c = n * 16 + lc;
    #pragma unroll
    for (int r = 0; r < 4; ++r) {
      int row = q4 * 4 + r;
      float fv = acc[n][r];
      float s2 = acc[n + 4][r];
      float e1 = __builtin_amdgcn_exp2f(-fv * L2E);
      float sig = __builtin_amdgcn_rcpf(1.0f + e1);
      float e2 = __builtin_amdgcn_exp2f(-fabsf(s2) * L2E);
      float sp2 = fmaxf(s2, 0.0f) + __builtin_amdgcn_logf(1.0f + e2) * LN2;
      mw[row * MS + c] = (bf16_t)(sig * sp2);
    }
  }
  __syncthreads();

  // segmented reduction: 16 segments x 8 rows, 32 col-pairs, packed u32 reads
  {
    const int cp = tid & 31;        // cols {2cp, 2cp+1}
    const int i0 = (tid >> 5) * 8;  // 8-row segment
    const uint32_t* m32 = (const uint32_t*)mT;
    uint32_t u = m32[i0 * (MS / 2) + cp];
    float rlo = blo(u), rhi = bhi(u);
    int cur = dstT[i0];
    #pragma unroll
    for (int i2 = 1; i2 < 8; ++i2) {
      int i = i0 + i2;
      uint32_t v = m32[i * (MS / 2) + cp];
      int d2 = dstT[i];
      float vlo = blo(v), vhi = bhi(v);
      if (d2 != cur) {
        atomicAdd(agg + (size_t)cur * F + 2 * cp,     rlo);
        atomicAdd(agg + (size_t)cur * F + 2 * cp + 1, rhi);
        rlo = vlo; rhi = vhi; cur = d2;
      } else {
        rlo += vlo; rhi += vhi;
      }
    }
    atomicAdd(agg + (size_t)cur * F + 2 * cp,     rlo);
    atomicAdd(agg + (size_t)cur * F + 2 * cp + 1, rhi);
  }
}

__global__ void k_update(float* __restrict__ agg, const float* __restrict__ gam,
                         const float* __restrict__ bet, const float* __restrict__ mu,
                         const float* __restrict__ var, float* __restrict__ h32,
                         bf16_t* __restrict__ hb, int layer) {
  int i = blockIdx.x * 256 + threadIdx.x;
  if (i >= NN * F) return;
  int c = i & 63;
  float sc = gam[layer * F + c] * rsqrtf(var[layer * F + c] + BN_EPS);
  float sh = bet[layer * F + c] - mu[layer * F + c] * sc;
  float v = agg[i] * sc + sh + h32[i];
  agg[i] = 0.0f;                 // pre-zero for next layer (memset at call start covers poison)
  v = fmaxf(v, 0.0f);
  h32[i] = v;
  hb[i] = (bf16_t)v;
}

__device__ __forceinline__ int lowb(const int* a, int n, int v) {
  int lo = 0, hi = n;
  while (lo < hi) { int mid = (lo + hi) >> 1; if (a[mid] < v) lo = mid + 1; else hi = mid; }
  return lo;
}

__global__ void k_pool_mlp(const float* __restrict__ h32, const int* __restrict__ batch,
                           const float* __restrict__ W1, const float* __restrict__ b1,
                           const float* __restrict__ W2, const float* __restrict__ b2,
                           float* __restrict__ out) {
  __shared__ float pooled[F];
  __shared__ float ps[HF];
  __shared__ float red[HF];
  const int gph = blockIdx.x;
  const int t = threadIdx.x;   // 128 threads
  const int lo = lowb(batch, NN, gph);
  const int hi = lowb(batch, NN, gph + 1);

  float s = 0.f;
  for (int i = lo + (t >> 6); i < hi; i += 2) s += h32[(size_t)i * F + (t & 63)];
  ps[t] = s;
  __syncthreads();
  if (t < F) {
    float tot = ps[t] + ps[t + F];
    pooled[t] = tot / fmaxf((float)(hi - lo), 1.0f);
  }
  __syncthreads();

  float a = b1[t];
  for (int c = 0; c < F; ++c) a += pooled[c] * W1[c * HF + t];
  a = fmaxf(a, 0.f);
  red[t] = a * W2[t];
  __syncthreads();
  for (int sdv = 64; sdv > 0; sdv >>= 1) {
    if (t < sdv) red[t] += red[t + sdv];
    __syncthreads();
  }
  if (t == 0) out[gph] = red[0] + b2[0];
}

extern "C" void kernel_launch(void* const* d_in, const int* in_sizes, int n_in,
                              void* d_out, int out_size, void* d_ws, size_t ws_size,
                              hipStream_t stream) {
  const int*   x    = (const int*)d_in[0];
  const int*   ei   = (const int*)d_in[1];
  const float* ea   = (const float*)d_in[2];
  const int*   batch= (const int*)d_in[3];
  const float* emb  = (const float*)d_in[4];
  const float* Wf   = (const float*)d_in[5];
  const float* bfb  = (const float*)d_in[6];
  const float* Ws   = (const float*)d_in[7];
  const float* bsb  = (const float*)d_in[8];
  const float* gam  = (const float*)d_in[9];
  const float* bet  = (const float*)d_in[10];
  const float* mu   = (const float*)d_in[11];
  const float* var  = (const float*)d_in[12];
  const float* W1   = (const float*)d_in[13];
  const float* b1   = (const float*)d_in[14];
  const float* W2   = (const float*)d_in[15];
  const float* b2   = (const float*)d_in[16];
  float* out = (float*)d_out;

  char* p = (char*)d_ws;
  auto take = [&](size_t bytes) { char* q = p; p += (bytes + 255) & ~(size_t)255; return q; };
  float*  h32  = (float*)take((size_t)NN * F * 4);
  bf16_t* hb   = (bf16_t*)take((size_t)NN * F * 2);
  float*  agg  = (float*)take((size_t)NN * F * 4);
  bf16_t* Wt   = (bf16_t*)take((size_t)NCONV * NC * ZIN * 2);
  int*    cnt  = (int*)take((size_t)NN * 4);
  int*    off  = (int*)take((size_t)NN * 4);
  int*    head = (int*)take((size_t)NN * 4);
  int*    srcs = (int*)take((size_t)NE * 4);
  int*    dsts = (int*)take((size_t)NE * 4);
  bf16_t* eas  = (bf16_t*)take((size_t)NE * ED * 2);

  k_embed<<<(NN * F + 255) / 256, 256, 0, stream>>>(x, emb, h32, hb);
  k_wprep<<<(NCONV * ZIN * NC + 255) / 256, 256, 0, stream>>>(Wf, Ws, Wt);

  // counting sort by dst (invariant across layers)
  hipMemsetAsync(cnt, 0, (size_t)NN * 4, stream);
  k_hist<<<(NE + 255) / 256, 256, 0, stream>>>(ei, cnt);
  k_scan<<<1, 1024, 0, stream>>>(cnt, off);
  hipMemcpyAsync(head, off, (size_t)NN * 4, hipMemcpyDeviceToDevice, stream);
  k_scatter<<<(NE + 255) / 256, 256, 0, stream>>>(ei, ea, head, srcs, dsts, eas);

  const size_t smem = 40960 + 512;  // 41472 B -> 3 blocks/CU
  hipFuncSetAttribute((const void*)k_edges, hipFuncAttributeMaxDynamicSharedMemorySize, (int)smem);

  hipMemsetAsync(agg, 0, (size_t)NN * F * 4, stream);   // covers 0xAA poison; k_update re-zeroes per layer
  for (int layer = 0; layer < NCONV; ++layer) {
    k_edges<<<NE / EB, 512, smem, stream>>>(srcs, dsts, eas, hb, Wt, bfb, bsb, agg, layer);
    k_update<<<(NN * F + 255) / 256, 256, 0, stream>>>(agg, gam, bet, mu, var, h32, hb, layer);
  }

  k_pool_mlp<<<NG, HF, 0, stream>>>(h32, batch, W1, b1, W2, b2, out);
}

// Round 7
// 728.774 us; speedup vs baseline: 1.2201x; 1.2201x over previous
//
#include <hip/hip_runtime.h>
#include <hip/hip_bf16.h>
#include <cstdint>

#define NN    50000
#define NE    1600000
#define NG    512
#define F     64        // ATOM_FEA
#define ED    32        // EDGE_DIM
#define ZIN   160       // 2F + ED
#define NC    128       // fused Wf|Ws output cols
#define HF    128       // H_FEA
#define NCONV 3
#define BN_EPS 1e-5f
#define MS    66        // mT row stride in bf16 (33 u32) -> conflict-light
#define NWG   (NE / 256)   // 6250 k_edges workgroups

typedef __bf16 bf16_t;
typedef bf16_t bf16x8 __attribute__((ext_vector_type(8)));
typedef float  f32x16 __attribute__((ext_vector_type(16)));

__device__ __forceinline__ float blo(uint32_t u) { union { uint32_t x; float f; } t; t.x = u << 16;          return t.f; }
__device__ __forceinline__ float bhi(uint32_t u) { union { uint32_t x; float f; } t; t.x = u & 0xffff0000u;  return t.f; }

__global__ void k_embed_hist(const int* __restrict__ x, const float* __restrict__ emb,
                             float* __restrict__ h32, bf16_t* __restrict__ hb,
                             const int* __restrict__ ei, int* __restrict__ cnt) {
  int i = blockIdx.x * 256 + threadIdx.x;
  if (i < NN * F) {
    int node = i >> 6, c = i & 63;
    float v = emb[x[node] * F + c];
    h32[i] = v;
    hb[i] = (bf16_t)v;
  }
  if (i < NE) atomicAdd(&cnt[ei[NE + i]], 1);
}

// Wt layout: pre-fragmented for 32x32x16 MFMA B-operand, per layer:
//   Wt[((l*10 + ks)*4 + n)*512 + lane*8 + idx]
//   lane: g=lane>>5, lr=lane&31; col c = n*32+lr; k = 16*ks + 4*g + 8*(idx>>2) + (idx&3)
__global__ void k_wprep(const float* __restrict__ Wf, const float* __restrict__ Ws,
                        bf16_t* __restrict__ Wt) {
  int i = blockIdx.x * 256 + threadIdx.x;  // NCONV*ZIN*NC = 61440
  if (i >= NCONV * ZIN * NC) return;
  int l = i / 20480, r = i % 20480;
  int ks = r / 2048, r2 = r % 2048;
  int n = r2 / 512, r3 = r2 % 512;
  int lane = r3 >> 3, idx = r3 & 7;
  int g = lane >> 5, lr = lane & 31;
  int c = n * 32 + lr;
  int k = 16 * ks + 4 * g + 8 * (idx >> 2) + (idx & 3);
  float v = (c < F) ? Wf[(l * ZIN + k) * F + c] : Ws[(l * ZIN + k) * F + (c - F)];
  Wt[i] = (bf16_t)v;
}

__global__ void k_scan(const int* __restrict__ cnt, int* __restrict__ off) {
  __shared__ int ts[1024];
  const int t = threadIdx.x;
  const int CH = 49;                 // 1024*49 = 50176 >= NN
  const int base = t * CH;
  int s = 0;
  for (int i = 0; i < CH; ++i) { int idx = base + i; if (idx < NN) s += cnt[idx]; }
  ts[t] = s;
  __syncthreads();
  for (int d = 1; d < 1024; d <<= 1) {
    int v = (t >= d) ? ts[t - d] : 0;
    __syncthreads();
    ts[t] += v;
    __syncthreads();
  }
  int run = (t == 0) ? 0 : ts[t - 1];
  for (int i = 0; i < CH; ++i) {
    int idx = base + i;
    if (idx < NN) { off[idx] = run; run += cnt[idx]; }
  }
}

__global__ void k_scatter(const int* __restrict__ ei, const float* __restrict__ ea,
                          int* __restrict__ head, int* __restrict__ srcs,
                          int* __restrict__ dsts, bf16_t* __restrict__ eas) {
  int e = blockIdx.x * 256 + threadIdx.x;
  if (e >= NE) return;
  int d = ei[NE + e], s = ei[e];
  int p = atomicAdd(&head[d], 1);
  dsts[p] = d; srcs[p] = s;
  const float* pa = ea + (size_t)e * ED;
  bf16_t* pe = eas + (size_t)p * ED;
  #pragma unroll
  for (int q = 0; q < ED; q += 8) {
    float4 x0 = *(const float4*)(pa + q), x1 = *(const float4*)(pa + q + 4);
    union { bf16_t h[8]; uint4 u; } pk;
    pk.h[0] = (bf16_t)x0.x; pk.h[1] = (bf16_t)x0.y; pk.h[2] = (bf16_t)x0.z; pk.h[3] = (bf16_t)x0.w;
    pk.h[4] = (bf16_t)x1.x; pk.h[5] = (bf16_t)x1.y; pk.h[6] = (bf16_t)x1.z; pk.h[7] = (bf16_t)x1.w;
    *(uint4*)(pe + q) = pk.u;
  }
}

// 512 threads, 8 waves, 256 edges/block (32 edge-rows per wave).
// LDS: Bsh 40960 + mT [256][66] bf16 33792 (SEPARATE -> no mid barriers) + dstT 1024 = 75776 B
// One barrier total (after B-stage); epilogue+walk are wave-local.
__launch_bounds__(512, 4)
__global__ void k_edges(const int* __restrict__ srcs, const int* __restrict__ dsts,
                        const bf16_t* __restrict__ eas, const bf16_t* __restrict__ hb,
                        const bf16_t* __restrict__ Wt,
                        const float* __restrict__ bfv, const float* __restrict__ bsv,
                        float* __restrict__ agg, int layer) {
  extern __shared__ char smem[];
  bf16_t* Bsh  = (bf16_t*)smem;                       // [20480] pre-fragmented W
  bf16_t* mT   = (bf16_t*)(smem + 40960);             // [256][MS] messages
  int*    dstT = (int*)(smem + 40960 + 33792);        // [256]

  const int tid = threadIdx.x;

  // bijective XCD-chunked swizzle: consecutive work -> same XCD (sorted-dst L2 locality)
  // NWG = 6250 = 8*781 + 2 -> q=781, r=2 (m204 bijective variant)
  const int orig = blockIdx.x;
  const int xcd  = orig & 7;
  const int wg   = ((xcd < 2) ? xcd * 782 : 2 * 782 + (xcd - 2) * 781) + (orig >> 3);
  const int e0   = wg * 256;

  const int w  = tid >> 6;
  const int l  = tid & 63;
  const int lr = l & 31;
  const int g  = l >> 5;
  const int e  = w * 32 + lr;

  // long-latency loads first
  const int dv = dsts[e0 + e];
  const int sv = srcs[e0 + e];
  dstT[e] = dv;                 // wave-private rows (both g-halves write same value)

  // per-lane bias values (folded into acc init via MFMA C-in)
  const float* bfl = bfv + layer * F;
  const float* bsl = bsv + layer * F;
  const float b0 = bfl[lr], b1 = bfl[lr + 32];
  const float s0 = bsl[lr], s1 = bsl[lr + 32];

  // gather A-fragments straight from global (fragment layout: lane=row, 8B strided by g-half)
  const char* dp = (const char*)(hb + (size_t)dv * F);
  const char* sp = (const char*)(hb + (size_t)sv * F);
  const char* ep = (const char*)(eas + (size_t)(e0 + e) * ED);
  uint2 dq[8], sq[8], eq[4];
  #pragma unroll
  for (int j = 0; j < 8; ++j) dq[j] = *(const uint2*)(dp + (2 * j + g) * 8);
  #pragma unroll
  for (int j = 0; j < 8; ++j) sq[j] = *(const uint2*)(sp + (2 * j + g) * 8);
  #pragma unroll
  for (int j = 0; j < 4; ++j) eq[j] = *(const uint2*)(ep + (2 * j + g) * 8);

  // stage B: 40960 B = 2560 uint4, 5 per thread
  {
    const uint4* Wg = (const uint4*)(Wt + (size_t)layer * NC * ZIN);
    uint4 breg[5];
    #pragma unroll
    for (int t = 0; t < 5; ++t) breg[t] = Wg[tid + t * 512];
    uint4* Bv = (uint4*)Bsh;
    #pragma unroll
    for (int t = 0; t < 5; ++t) Bv[tid + t * 512] = breg[t];
  }
  __syncthreads();   // the ONLY barrier: Bsh visible to all waves

  f32x16 acc[4];
  #pragma unroll
  for (int q = 0; q < 16; ++q) { acc[0][q] = b0; acc[1][q] = b1; acc[2][q] = s0; acc[3][q] = s1; }

  #pragma unroll
  for (int ks = 0; ks < 10; ++ks) {
    union { uint2 u[2]; bf16x8 v; } a;
    a.u[0] = (ks < 4) ? dq[2 * ks]     : (ks < 8) ? sq[2 * (ks - 4)]     : eq[2 * (ks - 8)];
    a.u[1] = (ks < 4) ? dq[2 * ks + 1] : (ks < 8) ? sq[2 * (ks - 4) + 1] : eq[2 * (ks - 8) + 1];
    #pragma unroll
    for (int n = 0; n < 4; ++n) {
      bf16x8 b = *(const bf16x8*)(Bsh + ((ks * 4 + n) * 64 + l) * 8);  // ds_read_b128, stride-1
      acc[n] = __builtin_amdgcn_mfma_f32_32x32x16_bf16(a.v, b, acc[n], 0, 0, 0);
    }
  }

  // epilogue (no barrier: mT rows are wave-private): m = sigmoid(f)*softplus(s) -> bf16 mT
  bf16_t* mw = mT + w * 32 * MS;
  const float L2E = 1.4426950408889634f, LN2 = 0.6931471805599453f;
  #pragma unroll
  for (int n = 0; n < 2; ++n) {
    const int c = n * 32 + lr;
    #pragma unroll
    for (int q = 0; q < 16; ++q) {
      int row = (q & 3) + 8 * (q >> 2) + 4 * g;   // verified 32x32 C/D row map
      float fv = acc[n][q];
      float s2 = acc[n + 2][q];
      float e1 = __builtin_amdgcn_exp2f(-fv * L2E);
      float sig = __builtin_amdgcn_rcpf(1.0f + e1);
      float e2 = __builtin_amdgcn_exp2f(-fabsf(s2) * L2E);
      float sp2 = fmaxf(s2, 0.0f) + __builtin_amdgcn_logf(1.0f + e2) * LN2;
      mw[row * MS + c] = (bf16_t)(sig * sp2);
    }
  }

  // wave-local fence: mT writes complete before walk reads (same-wave LDS is in-order;
  // lgkmcnt(0) + sched_barrier pins the compiler, rule #18)
  asm volatile("s_waitcnt lgkmcnt(0)" ::: "memory");
  __builtin_amdgcn_sched_barrier(0);

  // segmented reduction (wave-local rows): 16-row segment x 32 col-pairs, packed u32 reads
  {
    const int cp = tid & 31;        // cols {2cp, 2cp+1}
    const int i0 = (tid >> 5) * 16; // rows [i0, i0+16) -- within this wave's 32 rows
    const uint32_t* m32 = (const uint32_t*)mT;
    uint32_t u = m32[i0 * (MS / 2) + cp];
    float rlo = blo(u), rhi = bhi(u);
    int cur = dstT[i0];
    for (int i = i0 + 1; i < i0 + 16; ++i) {
      uint32_t v = m32[i * (MS / 2) + cp];
      int d2 = dstT[i];
      float vlo = blo(v), vhi = bhi(v);
      if (d2 != cur) {
        atomicAdd(agg + (size_t)cur * F + 2 * cp,     rlo);
        atomicAdd(agg + (size_t)cur * F + 2 * cp + 1, rhi);
        rlo = vlo; rhi = vhi; cur = d2;
      } else {
        rlo += vlo; rhi += vhi;
      }
    }
    atomicAdd(agg + (size_t)cur * F + 2 * cp,     rlo);
    atomicAdd(agg + (size_t)cur * F + 2 * cp + 1, rhi);
  }
}

__global__ void k_update(float* __restrict__ agg, const float* __restrict__ gam,
                         const float* __restrict__ bet, const float* __restrict__ mu,
                         const float* __restrict__ var, float* __restrict__ h32,
                         bf16_t* __restrict__ hb, int layer) {
  int i = blockIdx.x * 256 + threadIdx.x;
  if (i >= NN * F) return;
  int c = i & 63;
  float sc = gam[layer * F + c] * rsqrtf(var[layer * F + c] + BN_EPS);
  float sh = bet[layer * F + c] - mu[layer * F + c] * sc;
  float v = agg[i] * sc + sh + h32[i];
  agg[i] = 0.0f;                 // pre-zero for next layer
  v = fmaxf(v, 0.0f);
  h32[i] = v;
  hb[i] = (bf16_t)v;
}

__device__ __forceinline__ int lowb(const int* a, int n, int v) {
  int lo = 0, hi = n;
  while (lo < hi) { int mid = (lo + hi) >> 1; if (a[mid] < v) lo = mid + 1; else hi = mid; }
  return lo;
}

__global__ void k_pool_mlp(const float* __restrict__ h32, const int* __restrict__ batch,
                           const float* __restrict__ W1, const float* __restrict__ b1,
                           const float* __restrict__ W2, const float* __restrict__ b2,
                           float* __restrict__ out) {
  __shared__ float pooled[F];
  __shared__ float ps[HF];
  __shared__ float red[HF];
  const int gph = blockIdx.x;
  const int t = threadIdx.x;   // 128 threads
  const int lo = lowb(batch, NN, gph);
  const int hi = lowb(batch, NN, gph + 1);

  float s = 0.f;
  for (int i = lo + (t >> 6); i < hi; i += 2) s += h32[(size_t)i * F + (t & 63)];
  ps[t] = s;
  __syncthreads();
  if (t < F) {
    float tot = ps[t] + ps[t + F];
    pooled[t] = tot / fmaxf((float)(hi - lo), 1.0f);
  }
  __syncthreads();

  float a = b1[t];
  for (int c = 0; c < F; ++c) a += pooled[c] * W1[c * HF + t];
  a = fmaxf(a, 0.f);
  red[t] = a * W2[t];
  __syncthreads();
  for (int sdv = 64; sdv > 0; sdv >>= 1) {
    if (t < sdv) red[t] += red[t + sdv];
    __syncthreads();
  }
  if (t == 0) out[gph] = red[0] + b2[0];
}

extern "C" void kernel_launch(void* const* d_in, const int* in_sizes, int n_in,
                              void* d_out, int out_size, void* d_ws, size_t ws_size,
                              hipStream_t stream) {
  const int*   x    = (const int*)d_in[0];
  const int*   ei   = (const int*)d_in[1];
  const float* ea   = (const float*)d_in[2];
  const int*   batch= (const int*)d_in[3];
  const float* emb  = (const float*)d_in[4];
  const float* Wf   = (const float*)d_in[5];
  const float* bfb  = (const float*)d_in[6];
  const float* Ws   = (const float*)d_in[7];
  const float* bsb  = (const float*)d_in[8];
  const float* gam  = (const float*)d_in[9];
  const float* bet  = (const float*)d_in[10];
  const float* mu   = (const float*)d_in[11];
  const float* var  = (const float*)d_in[12];
  const float* W1   = (const float*)d_in[13];
  const float* b1   = (const float*)d_in[14];
  const float* W2   = (const float*)d_in[15];
  const float* b2   = (const float*)d_in[16];
  float* out = (float*)d_out;

  char* p = (char*)d_ws;
  auto take = [&](size_t bytes) { char* q = p; p += (bytes + 255) & ~(size_t)255; return q; };
  float*  h32  = (float*)take((size_t)NN * F * 4);
  bf16_t* hb   = (bf16_t*)take((size_t)NN * F * 2);
  float*  agg  = (float*)take((size_t)NN * F * 4);
  bf16_t* Wt   = (bf16_t*)take((size_t)NCONV * NC * ZIN * 2);
  int*    cnt  = (int*)take((size_t)NN * 4);
  int*    off  = (int*)take((size_t)NN * 4);
  int*    head = (int*)take((size_t)NN * 4);
  int*    srcs = (int*)take((size_t)NE * 4);
  int*    dsts = (int*)take((size_t)NE * 4);
  bf16_t* eas  = (bf16_t*)take((size_t)NE * ED * 2);

  hipMemsetAsync(cnt, 0, (size_t)NN * 4, stream);
  k_embed_hist<<<(NN * F + 255) / 256, 256, 0, stream>>>(x, emb, h32, hb, ei, cnt);
  k_wprep<<<(NCONV * ZIN * NC + 255) / 256, 256, 0, stream>>>(Wf, Ws, Wt);

  k_scan<<<1, 1024, 0, stream>>>(cnt, off);
  hipMemcpyAsync(head, off, (size_t)NN * 4, hipMemcpyDeviceToDevice, stream);
  k_scatter<<<(NE + 255) / 256, 256, 0, stream>>>(ei, ea, head, srcs, dsts, eas);

  const size_t smem = 40960 + 33792 + 1024;  // 75776 B -> 2 blocks/CU
  hipFuncSetAttribute((const void*)k_edges, hipFuncAttributeMaxDynamicSharedMemorySize, (int)smem);

  hipMemsetAsync(agg, 0, (size_t)NN * F * 4, stream);   // covers 0xAA poison; k_update re-zeroes per layer
  for (int layer = 0; layer < NCONV; ++layer) {
    k_edges<<<NWG, 512, smem, stream>>>(srcs, dsts, eas, hb, Wt, bfb, bsb, agg, layer);
    k_update<<<(NN * F + 255) / 256, 256, 0, stream>>>(agg, gam, bet, mu, var, h32, hb, layer);
  }

  k_pool_mlp<<<NG, HF, 0, stream>>>(h32, batch, W1, b1, W2, b2, out);
}

// Round 8
// 706.355 us; speedup vs baseline: 1.2588x; 1.0317x over previous
//
#include <hip/hip_runtime.h>
#include <hip/hip_bf16.h>
#include <cstdint>

#define NN    50000
#define NE    1600000
#define NG    512
#define F     64        // ATOM_FEA
#define ED    32        // EDGE_DIM
#define ZIN   160       // 2F + ED
#define NC    128       // fused Wf|Ws output cols
#define HF    128       // H_FEA
#define NCONV 3
#define BN_EPS 1e-5f
#define NWG   (NE / 256)   // 6250 k_edges workgroups

typedef __bf16 bf16_t;
typedef bf16_t bf16x8 __attribute__((ext_vector_type(8)));
typedef float  f32x16 __attribute__((ext_vector_type(16)));

__global__ void k_embed_hist(const int* __restrict__ x, const float* __restrict__ emb,
                             float* __restrict__ h32, bf16_t* __restrict__ hb,
                             const int* __restrict__ ei, int* __restrict__ cnt) {
  int i = blockIdx.x * 256 + threadIdx.x;
  if (i < NN * F) {
    int node = i >> 6, c = i & 63;
    float v = emb[x[node] * F + c];
    h32[i] = v;
    hb[i] = (bf16_t)v;
  }
  if (i < NE) atomicAdd(&cnt[ei[NE + i]], 1);
}

// Wt layout: pre-fragmented for 32x32x16 MFMA B-operand, per layer:
//   Wt[((l*10 + ks)*4 + n)*512 + lane*8 + idx]
//   lane: g=lane>>5, lr=lane&31; col c = n*32+lr; k = 16*ks + 4*g + 8*(idx>>2) + (idx&3)
__global__ void k_wprep(const float* __restrict__ Wf, const float* __restrict__ Ws,
                        bf16_t* __restrict__ Wt) {
  int i = blockIdx.x * 256 + threadIdx.x;  // NCONV*ZIN*NC = 61440
  if (i >= NCONV * ZIN * NC) return;
  int l = i / 20480, r = i % 20480;
  int ks = r / 2048, r2 = r % 2048;
  int n = r2 / 512, r3 = r2 % 512;
  int lane = r3 >> 3, idx = r3 & 7;
  int g = lane >> 5, lr = lane & 31;
  int c = n * 32 + lr;
  int k = 16 * ks + 4 * g + 8 * (idx >> 2) + (idx & 3);
  float v = (c < F) ? Wf[(l * ZIN + k) * F + c] : Ws[(l * ZIN + k) * F + (c - F)];
  Wt[i] = (bf16_t)v;
}

__global__ void k_scan(const int* __restrict__ cnt, int* __restrict__ off,
                       int* __restrict__ head) {
  __shared__ int ts[1024];
  const int t = threadIdx.x;
  const int CH = 49;                 // 1024*49 = 50176 >= NN
  const int base = t * CH;
  int s = 0;
  for (int i = 0; i < CH; ++i) { int idx = base + i; if (idx < NN) s += cnt[idx]; }
  ts[t] = s;
  __syncthreads();
  for (int d = 1; d < 1024; d <<= 1) {
    int v = (t >= d) ? ts[t - d] : 0;
    __syncthreads();
    ts[t] += v;
    __syncthreads();
  }
  int run = (t == 0) ? 0 : ts[t - 1];
  for (int i = 0; i < CH; ++i) {
    int idx = base + i;
    if (idx < NN) { off[idx] = run; head[idx] = run; run += cnt[idx]; }
  }
}

__global__ void k_scatter(const int* __restrict__ ei, const float* __restrict__ ea,
                          int* __restrict__ head, int* __restrict__ srcs,
                          int* __restrict__ dsts, bf16_t* __restrict__ eas) {
  int e = blockIdx.x * 256 + threadIdx.x;
  if (e >= NE) return;
  int d = ei[NE + e], s = ei[e];
  int p = atomicAdd(&head[d], 1);
  dsts[p] = d; srcs[p] = s;
  const float* pa = ea + (size_t)e * ED;
  bf16_t* pe = eas + (size_t)p * ED;
  #pragma unroll
  for (int q = 0; q < ED; q += 8) {
    float4 x0 = *(const float4*)(pa + q), x1 = *(const float4*)(pa + q + 4);
    union { bf16_t h[8]; uint4 u; } pk;
    pk.h[0] = (bf16_t)x0.x; pk.h[1] = (bf16_t)x0.y; pk.h[2] = (bf16_t)x0.z; pk.h[3] = (bf16_t)x0.w;
    pk.h[4] = (bf16_t)x1.x; pk.h[5] = (bf16_t)x1.y; pk.h[6] = (bf16_t)x1.z; pk.h[7] = (bf16_t)x1.w;
    *(uint4*)(pe + q) = pk.u;
  }
}

// 512 threads, 8 waves, 256 edges/block (32 edge-rows per wave).
// LDS: Bsh 40960 only. One barrier (B-stage). Epilogue + segmented reduction fully
// in registers: MFMA C layout gives lane l (col lr) rows {0-3,8-11,16-19,24-27}+4g;
// runs found by ballot over per-lane dv; per run 16 predicated adds + shfl_xor(32) + 2 atomics.
__launch_bounds__(512, 4)
__global__ void k_edges(const int* __restrict__ srcs, const int* __restrict__ dsts,
                        const bf16_t* __restrict__ eas, const bf16_t* __restrict__ hb,
                        const bf16_t* __restrict__ Wt,
                        const float* __restrict__ bfv, const float* __restrict__ bsv,
                        float* __restrict__ agg, int layer) {
  extern __shared__ char smem[];
  bf16_t* Bsh = (bf16_t*)smem;                       // [20480] pre-fragmented W

  const int tid = threadIdx.x;

  // bijective XCD-chunked swizzle: consecutive work -> same XCD (sorted-dst L2 locality)
  // NWG = 6250 = 8*781 + 2 -> q=781, r=2
  const int orig = blockIdx.x;
  const int xcd  = orig & 7;
  const int wg   = ((xcd < 2) ? xcd * 782 : 2 * 782 + (xcd - 2) * 781) + (orig >> 3);
  const int e0   = wg * 256;

  const int w  = tid >> 6;
  const int l  = tid & 63;
  const int lr = l & 31;
  const int g  = l >> 5;
  const int e  = w * 32 + lr;

  // long-latency loads first
  const int dv = dsts[e0 + e];
  const int sv = srcs[e0 + e];

  // per-lane bias values (folded into acc init via MFMA C-in)
  const float* bfl = bfv + layer * F;
  const float* bsl = bsv + layer * F;
  const float b0 = bfl[lr], b1 = bfl[lr + 32];
  const float s0b = bsl[lr], s1b = bsl[lr + 32];

  // gather A-fragments straight from global (fragment layout: lane=row, 8B strided by g-half)
  const char* dp = (const char*)(hb + (size_t)dv * F);
  const char* sp = (const char*)(hb + (size_t)sv * F);
  const char* ep = (const char*)(eas + (size_t)(e0 + e) * ED);
  uint2 dq[8], sq[8], eq[4];
  #pragma unroll
  for (int j = 0; j < 8; ++j) dq[j] = *(const uint2*)(dp + (2 * j + g) * 8);
  #pragma unroll
  for (int j = 0; j < 8; ++j) sq[j] = *(const uint2*)(sp + (2 * j + g) * 8);
  #pragma unroll
  for (int j = 0; j < 4; ++j) eq[j] = *(const uint2*)(ep + (2 * j + g) * 8);

  // stage B: 40960 B = 2560 uint4, 5 per thread
  {
    const uint4* Wg = (const uint4*)(Wt + (size_t)layer * NC * ZIN);
    uint4 breg[5];
    #pragma unroll
    for (int t = 0; t < 5; ++t) breg[t] = Wg[tid + t * 512];
    uint4* Bv = (uint4*)Bsh;
    #pragma unroll
    for (int t = 0; t < 5; ++t) Bv[tid + t * 512] = breg[t];
  }
  __syncthreads();   // the ONLY barrier: Bsh visible to all waves

  f32x16 acc[4];
  #pragma unroll
  for (int q = 0; q < 16; ++q) { acc[0][q] = b0; acc[1][q] = b1; acc[2][q] = s0b; acc[3][q] = s1b; }

  #pragma unroll
  for (int ks = 0; ks < 10; ++ks) {
    union { uint2 u[2]; bf16x8 v; } a;
    a.u[0] = (ks < 4) ? dq[2 * ks]     : (ks < 8) ? sq[2 * (ks - 4)]     : eq[2 * (ks - 8)];
    a.u[1] = (ks < 4) ? dq[2 * ks + 1] : (ks < 8) ? sq[2 * (ks - 4) + 1] : eq[2 * (ks - 8) + 1];
    #pragma unroll
    for (int n = 0; n < 4; ++n) {
      bf16x8 b = *(const bf16x8*)(Bsh + ((ks * 4 + n) * 64 + l) * 8);  // ds_read_b128, stride-1
      acc[n] = __builtin_amdgcn_mfma_f32_32x32x16_bf16(a.v, b, acc[n], 0, 0, 0);
    }
  }

  // epilogue in registers: mv0[q] = m[row(q,g)][lr], mv1[q] = m[row(q,g)][32+lr]
  const float L2E = 1.4426950408889634f, LN2 = 0.6931471805599453f;
  float mv0[16], mv1[16];
  #pragma unroll
  for (int q = 0; q < 16; ++q) {
    float f0 = acc[0][q], f1 = acc[1][q];
    float s2a = acc[2][q], s2c = acc[3][q];
    float sg0 = __builtin_amdgcn_rcpf(1.0f + __builtin_amdgcn_exp2f(-f0 * L2E));
    float sg1 = __builtin_amdgcn_rcpf(1.0f + __builtin_amdgcn_exp2f(-f1 * L2E));
    float sp0 = fmaxf(s2a, 0.0f) + __builtin_amdgcn_logf(1.0f + __builtin_amdgcn_exp2f(-fabsf(s2a) * L2E)) * LN2;
    float sp1 = fmaxf(s2c, 0.0f) + __builtin_amdgcn_logf(1.0f + __builtin_amdgcn_exp2f(-fabsf(s2c) * L2E)) * LN2;
    mv0[q] = sg0 * sp0;
    mv1[q] = sg1 * sp1;
  }

  // in-register segmented reduction over sorted-dst runs within this wave's 32-row window
  {
    const int dvp = __shfl(dv, l - 1);   // previous row's dst (lr>0 only)
    uint32_t bmask = ((uint32_t)__ballot(lr > 0 && dv != dvp)) | 1u;
    while (bmask) {
      const int a = __ffs(bmask) - 1;
      bmask &= bmask - 1;
      const int b = bmask ? (__ffs(bmask) - 1) : 32;
      const int dcur = __shfl(dv, a);
      float r0 = 0.0f, r1 = 0.0f;
      #pragma unroll
      for (int q = 0; q < 16; ++q) {
        const int row = (q & 3) + 8 * (q >> 2) + 4 * g;   // verified 32x32 C/D row map
        const bool in = (row >= a) && (row < b);
        r0 += in ? mv0[q] : 0.0f;
        r1 += in ? mv1[q] : 0.0f;
      }
      r0 += __shfl_xor(r0, 32);
      r1 += __shfl_xor(r1, 32);
      if (g == 0) {
        atomicAdd(agg + (size_t)dcur * F + lr,      r0);
        atomicAdd(agg + (size_t)dcur * F + 32 + lr, r1);
      }
    }
  }
}

__global__ void k_update(float* __restrict__ agg, const float* __restrict__ gam,
                         const float* __restrict__ bet, const float* __restrict__ mu,
                         const float* __restrict__ var, float* __restrict__ h32,
                         bf16_t* __restrict__ hb, int layer) {
  int i = blockIdx.x * 256 + threadIdx.x;
  if (i >= NN * F) return;
  int c = i & 63;
  float sc = gam[layer * F + c] * rsqrtf(var[layer * F + c] + BN_EPS);
  float sh = bet[layer * F + c] - mu[layer * F + c] * sc;
  float v = agg[i] * sc + sh + h32[i];
  agg[i] = 0.0f;                 // pre-zero for next layer
  v = fmaxf(v, 0.0f);
  h32[i] = v;
  hb[i] = (bf16_t)v;
}

__device__ __forceinline__ int lowb(const int* a, int n, int v) {
  int lo = 0, hi = n;
  while (lo < hi) { int mid = (lo + hi) >> 1; if (a[mid] < v) lo = mid + 1; else hi = mid; }
  return lo;
}

__global__ void k_pool_mlp(const float* __restrict__ h32, const int* __restrict__ batch,
                           const float* __restrict__ W1, const float* __restrict__ b1,
                           const float* __restrict__ W2, const float* __restrict__ b2,
                           float* __restrict__ out) {
  __shared__ float pooled[F];
  __shared__ float ps[HF];
  __shared__ float red[HF];
  const int gph = blockIdx.x;
  const int t = threadIdx.x;   // 128 threads
  const int lo = lowb(batch, NN, gph);
  const int hi = lowb(batch, NN, gph + 1);

  float s = 0.f;
  for (int i = lo + (t >> 6); i < hi; i += 2) s += h32[(size_t)i * F + (t & 63)];
  ps[t] = s;
  __syncthreads();
  if (t < F) {
    float tot = ps[t] + ps[t + F];
    pooled[t] = tot / fmaxf((float)(hi - lo), 1.0f);
  }
  __syncthreads();

  float a = b1[t];
  for (int c = 0; c < F; ++c) a += pooled[c] * W1[c * HF + t];
  a = fmaxf(a, 0.f);
  red[t] = a * W2[t];
  __syncthreads();
  for (int sdv = 64; sdv > 0; sdv >>= 1) {
    if (t < sdv) red[t] += red[t + sdv];
    __syncthreads();
  }
  if (t == 0) out[gph] = red[0] + b2[0];
}

extern "C" void kernel_launch(void* const* d_in, const int* in_sizes, int n_in,
                              void* d_out, int out_size, void* d_ws, size_t ws_size,
                              hipStream_t stream) {
  const int*   x    = (const int*)d_in[0];
  const int*   ei   = (const int*)d_in[1];
  const float* ea   = (const float*)d_in[2];
  const int*   batch= (const int*)d_in[3];
  const float* emb  = (const float*)d_in[4];
  const float* Wf   = (const float*)d_in[5];
  const float* bfb  = (const float*)d_in[6];
  const float* Ws   = (const float*)d_in[7];
  const float* bsb  = (const float*)d_in[8];
  const float* gam  = (const float*)d_in[9];
  const float* bet  = (const float*)d_in[10];
  const float* mu   = (const float*)d_in[11];
  const float* var  = (const float*)d_in[12];
  const float* W1   = (const float*)d_in[13];
  const float* b1   = (const float*)d_in[14];
  const float* W2   = (const float*)d_in[15];
  const float* b2   = (const float*)d_in[16];
  float* out = (float*)d_out;

  char* p = (char*)d_ws;
  auto take = [&](size_t bytes) { char* q = p; p += (bytes + 255) & ~(size_t)255; return q; };
  float*  h32  = (float*)take((size_t)NN * F * 4);
  bf16_t* hb   = (bf16_t*)take((size_t)NN * F * 2);
  float*  agg  = (float*)take((size_t)NN * F * 4);
  bf16_t* Wt   = (bf16_t*)take((size_t)NCONV * NC * ZIN * 2);
  int*    cnt  = (int*)take((size_t)NN * 4);
  int*    off  = (int*)take((size_t)NN * 4);
  int*    head = (int*)take((size_t)NN * 4);
  int*    srcs = (int*)take((size_t)NE * 4);
  int*    dsts = (int*)take((size_t)NE * 4);
  bf16_t* eas  = (bf16_t*)take((size_t)NE * ED * 2);

  hipMemsetAsync(cnt, 0, (size_t)NN * 4, stream);
  k_embed_hist<<<(NN * F + 255) / 256, 256, 0, stream>>>(x, emb, h32, hb, ei, cnt);
  k_wprep<<<(NCONV * ZIN * NC + 255) / 256, 256, 0, stream>>>(Wf, Ws, Wt);

  k_scan<<<1, 1024, 0, stream>>>(cnt, off, head);
  k_scatter<<<(NE + 255) / 256, 256, 0, stream>>>(ei, ea, head, srcs, dsts, eas);

  const size_t smem = 40960;  // Bsh only
  hipFuncSetAttribute((const void*)k_edges, hipFuncAttributeMaxDynamicSharedMemorySize, (int)smem);

  hipMemsetAsync(agg, 0, (size_t)NN * F * 4, stream);   // covers 0xAA poison; k_update re-zeroes per layer
  for (int layer = 0; layer < NCONV; ++layer) {
    k_edges<<<NWG, 512, smem, stream>>>(srcs, dsts, eas, hb, Wt, bfb, bsb, agg, layer);
    k_update<<<(NN * F + 255) / 256, 256, 0, stream>>>(agg, gam, bet, mu, var, h32, hb, layer);
  }

  k_pool_mlp<<<NG, HF, 0, stream>>>(h32, batch, W1, b1, W2, b2, out);
}